// Round 3
// baseline (1826.618 us; speedup 1.0000x reference)
//
#include <hip/hip_runtime.h>
#include <stdint.h>

#define HH 128
#define WW 128
#define NIMG 32
#define CH 16
#define TILE 16
#define LW 20            // 16 + 2*2 halo
#define LA (LW * LW)     // 400 floats per channel plane
#define NUM_ITER 30
#define THR 0.1f
#define HWSZ (HH * WW)

#define PSTR 52                        // P/H row stride in bf16 elems (104 B)
#define CS_BYTES (17 * LA * 4)         // 27200 B: 17 planes (phases A-D1)
#define GATE_OFF CS_BYTES              // gate array after cs/Ph overlay
#define SMEM_BYTES (CS_BYTES + 1024)   // 28224 B -> 5 blocks/CU

typedef __attribute__((ext_vector_type(8))) short bf16x8;
typedef __attribute__((ext_vector_type(4))) float f32x4;
typedef __attribute__((ext_vector_type(4))) short sh4;

__device__ __forceinline__ unsigned short f2bf(float x) {
    union { float f; unsigned u; } v; v.f = x;
    return (unsigned short)((v.u + 0x7fffu + ((v.u >> 16) & 1u)) >> 16);  // RNE
}
__device__ __forceinline__ float bf2f(unsigned short h) {
    union { unsigned u; float f; } v; v.u = ((unsigned)h) << 16; return v.f;
}
__device__ __forceinline__ bf16x8 mk8(sh4 a, sh4 b) {
    bf16x8 r;
    r[0] = a.x; r[1] = a.y; r[2] = a.z; r[3] = a.w;
    r[4] = b.x; r[5] = b.y; r[6] = b.z; r[7] = b.w;
    return r;
}
__device__ __forceinline__ sh4 ld4(const unsigned short* p) {
    return *(const sh4*)p;
}

// ---------------- init: build 16-ch cell state from 10-ch input ----------------
__global__ __launch_bounds__(256) void init_kernel(const float* __restrict__ inp,
                                                   float* __restrict__ cell) {
    int i = blockIdx.x * 256 + threadIdx.x;
    if (i >= NIMG * CH * HWSZ) return;
    int hw = i % HWSZ;
    int c  = (i / HWSZ) % CH;
    int n  = i / (CH * HWSZ);
    float v;
    if (c == 0)       v = 1.0f - inp[(n * 10 + 0) * HWSZ + hw];
    else if (c <= 10) v = inp[(n * 10 + (c - 1)) * HWSZ + hw];
    else              v = 0.0f;
    cell[i] = v;
}

// ---------------- weight prepack: bf16 hi/lo split, row-major ----
__global__ void prepack(const float* __restrict__ w1, const float* __restrict__ w2,
                        unsigned short* __restrict__ w1h, unsigned short* __restrict__ w1l,
                        unsigned short* __restrict__ w2h, unsigned short* __restrict__ w2l) {
    int i = threadIdx.x;
    for (int k = i; k < 48 * 48; k += 256) {
        float f = w1[k];
        unsigned short h = f2bf(f);
        w1h[k] = h;
        w1l[k] = f2bf(f - bf2f(h));
    }
    for (int k = i; k < 16 * 48; k += 256) {
        float f = w2[k];
        unsigned short h = f2bf(f);
        w2h[k] = h;
        w2l[k] = f2bf(f - bf2f(h));
    }
}

// perception: p[0..15]=center, p[16..31]=sobel-x, p[32..47]=sobel-y
__device__ __forceinline__ void perception_at(const float* cs, int base, float* p) {
#pragma unroll
    for (int c = 0; c < CH; ++c) {
        const float* cc = cs + c * LA;
        float c00 = cc[base - LW - 1], c01 = cc[base - LW], c02 = cc[base - LW + 1];
        float c10 = cc[base - 1],      c11 = cc[base],      c12 = cc[base + 1];
        float c20 = cc[base + LW - 1], c21 = cc[base + LW], c22 = cc[base + LW + 1];
        p[c]      = c11;
        p[16 + c] = (c02 - c00 + 2.0f * (c12 - c10) + c22 - c20) * 0.125f;
        p[32 + c] = (c20 - c00 + 2.0f * (c21 - c01) + c22 - c02) * 0.125f;
    }
}

// ---------------- one fused CA step (MFMA matmuls, R3) ----------------
// LDS: cs (27200 B, phases A-D1) overlaid by Ph bf16 [256][52] (26624 B,
// D2 onward); gate[256] fp32 at +27200. Total 28224 B -> 5 blocks/CU.
// Residual path is exact fp32: raw center reloaded from global (L2-hot) x
// gate factor, so dropping the P-lo plane only perturbs the matmul path
// (~5e-4 on h, damped by w2's 0.02 scale).
// Barriers: 3. D2 writes / D3 B-reads / D4 H-writes / D5 H-reads all touch
// wave-private Ph rows [64wv,64wv+64) -> in-order DS pipe, no barrier.
__global__ __launch_bounds__(256, 5) void step_kernel(
    const float* __restrict__ cin, float* __restrict__ cout,
    const uint8_t* __restrict__ pre_in, uint8_t* __restrict__ pre_out,
    const unsigned short* __restrict__ w1h_, const unsigned short* __restrict__ w1l_,
    const unsigned short* __restrict__ w2h_, const unsigned short* __restrict__ w2l_,
    int gate) {

    __shared__ __align__(16) char smem[SMEM_BYTES];
    float* cs = (float*)smem;                       // 17 planes x 400 floats
    unsigned short* Ph = (unsigned short*)smem;     // [256][PSTR] bf16 (overlays cs)
    float* gateArr = (float*)(smem + GATE_OFF);     // [256] gate factor, inner 16x16

    const int tid = threadIdx.x;
    const int tx = tid & 15, ty = tid >> 4;
    const int lane = tid & 63;
    const int wv = tid >> 6;            // wave id: pixels [64*wv, 64*wv+64)
    const int px = lane & 15;           // col within 16-tile
    const int kc = lane >> 4;           // k-chunk id (0..3)
    const int bx = blockIdx.x * TILE, by = blockIdx.y * TILE;
    const int n = blockIdx.z;
    const float* cbase = cin + (size_t)n * CH * HWSZ;
    const uint8_t* pbase = pre_in + (size_t)n * HWSZ;

    // ---- hoisted coords: full 20x20 positions (raw ch0), two per thread ----
    const int lyA = tid / 20, lxA = tid % 20;
    const int gyA = by + lyA - 2, gxA = bx + lxA - 2;
    const bool okA = ((unsigned)gyA < HH) && ((unsigned)gxA < WW);
    const int offA = gyA * WW + gxA;

    const int rB = tid + 256;                  // valid when tid < 144
    const int lyB = rB / 20, lxB = rB % 20;
    const int gyB = by + lyB - 2, gxB = bx + lxB - 2;
    const bool okB = ((unsigned)gyB < HH) && ((unsigned)gxB < WW);
    const int offB = gyB * WW + gxB;

    // ---- hoisted coords: 18x18 region positions, two per thread ----
    const int j0 = tid;                        // always < 324
    const int jy0 = j0 / 18, jx0 = j0 % 18;
    const int gy0 = by + jy0 - 1, gx0 = bx + jx0 - 1;
    const bool ok0 = ((unsigned)gy0 < HH) && ((unsigned)gx0 < WW);
    const int goff0 = gy0 * WW + gx0;
    const int lpos0 = (jy0 + 1) * LW + (jx0 + 1);
    const bool in0 = ((unsigned)(jy0 - 1) < 16) && ((unsigned)(jx0 - 1) < 16);

    const int j1 = tid + 256;                  // valid when tid < 68
    const int jy1 = j1 / 18, jx1 = j1 % 18;
    const int gy1 = by + jy1 - 1, gx1 = bx + jx1 - 1;
    const bool ok1 = ((unsigned)gy1 < HH) && ((unsigned)gx1 < WW);
    const int goff1 = gy1 * WW + gx1;
    const int lpos1 = (jy1 + 1) * LW + (jx1 + 1);
    const bool in1 = ((unsigned)(jy1 - 1) < 16) && ((unsigned)(jx1 - 1) < 16);
    const bool hasB = (tid < 68);

    // ---- A: stage raw ch0 (plane 16) AND pre-issue all global loads ----
    cs[CH * LA + tid] = okA ? cbase[offA] : 0.0f;
    if (tid < 144) cs[CH * LA + rB] = okB ? cbase[offB] : 0.0f;

    // raw center values for this lane's D5 output assignment (exact residual):
    // pixel (by+4wv+t, bx+px), channels 4kc+r. Always in-bounds. L2-hot.
    float raw[4][4];
#pragma unroll
    for (int t = 0; t < 4; ++t) {
        const float* rp = cbase + (size_t)(by + 4 * wv + t) * WW + bx + px;
#pragma unroll
        for (int r = 0; r < 4; ++r)
            raw[t][r] = rp[(size_t)(4 * kc + r) * HWSZ];
    }

    float st0[CH - 1];
    {
        const float* gp = cbase + goff0;
#pragma unroll
        for (int c = 1; c < CH; ++c) st0[c - 1] = ok0 ? gp[c * HWSZ] : 0.0f;
    }
    int pv0 = 1;
    if (gate) pv0 = ok0 ? (int)pbase[goff0] : 0;

    float st1[CH - 1];
    int pv1 = 1;
    if (hasB) {
        const float* gp = cbase + goff1;
#pragma unroll
        for (int c = 1; c < CH; ++c) st1[c - 1] = ok1 ? gp[c * HWSZ] : 0.0f;
        if (gate) pv1 = ok1 ? (int)pbase[goff1] : 0;
    }
    __syncthreads();   // sync1

    // ---- B+C fused: gate from raw plane 16; gated writes to planes 0..15;
    //      gate factor for inner pixels saved to gateArr ----
    {
        const float* rp = cs + CH * LA;
        float pm = -1e30f;
#pragma unroll
        for (int dy = -1; dy <= 1; ++dy)
#pragma unroll
            for (int dx = -1; dx <= 1; ++dx)
                pm = fmaxf(pm, rp[lpos0 + dy * LW + dx]);
        float g0 = 1.0f;
        if (gate) g0 = (pv0 && pm > THR) ? 1.0f : 0.0f;
        cs[lpos0] = rp[lpos0] * g0;
#pragma unroll
        for (int c = 1; c < CH; ++c) cs[c * LA + lpos0] = st0[c - 1] * g0;
        if (in0) gateArr[(jy0 - 1) * 16 + (jx0 - 1)] = g0;
    }
    if (hasB) {
        const float* rp = cs + CH * LA;
        float pm = -1e30f;
#pragma unroll
        for (int dy = -1; dy <= 1; ++dy)
#pragma unroll
            for (int dx = -1; dx <= 1; ++dx)
                pm = fmaxf(pm, rp[lpos1 + dy * LW + dx]);
        float g1 = 1.0f;
        if (gate) g1 = (pv1 && pm > THR) ? 1.0f : 0.0f;
        cs[lpos1] = rp[lpos1] * g1;
#pragma unroll
        for (int c = 1; c < CH; ++c) cs[c * LA + lpos1] = st1[c - 1] * g1;
        if (in1) gateArr[(jy1 - 1) * 16 + (jx1 - 1)] = g1;
    }
    __syncthreads();   // sync2

    // ---- D1: pre(i) bits + per-thread perception (reads cs) ----
    const int base = (ty + 2) * LW + (tx + 2);
    float pm = -1e30f;
#pragma unroll
    for (int dy = -1; dy <= 1; ++dy)
#pragma unroll
        for (int dx = -1; dx <= 1; ++dx)
            pm = fmaxf(pm, cs[base + dy * LW + dx]);
    pre_out[(size_t)n * HWSZ + (size_t)(by + ty) * WW + (bx + tx)] = (pm > THR) ? 1 : 0;

    float p[48];
    perception_at(cs, base, p);
    __syncthreads();   // sync3: all cs reads done; Ph may now overlay cs

    // ---- D2: p -> bf16 hi into LDS (row = tid; wave-private rows) ----
    {
        unsigned short* hrow = Ph + tid * PSTR;
#pragma unroll
        for (int j = 0; j < 12; ++j) {
            sh4 hv;
            hv.x = (short)f2bf(p[4 * j + 0]);
            hv.y = (short)f2bf(p[4 * j + 1]);
            hv.z = (short)f2bf(p[4 * j + 2]);
            hv.w = (short)f2bf(p[4 * j + 3]);
            *(sh4*)(hrow + 4 * j) = hv;
        }
    }
    // no barrier: D3 B-reads are wave-private rows, DS pipe is in-order per wave

    // ---- D3: h = relu(w1 x P) via MFMA (2-product: (w1h+w1l) x Phi) ----
    const sh4 z4 = (sh4)0;
    const bf16x8 zero8 = mk8(z4, z4);

    f32x4 acc[3][4];
#pragma unroll
    for (int m = 0; m < 3; ++m)
#pragma unroll
        for (int t = 0; t < 4; ++t) acc[m][t] = 0.0f;

#pragma unroll
    for (int m = 0; m < 3; ++m) {
        const unsigned short* ah = w1h_ + (16 * m + px) * 48;
        const unsigned short* al = w1l_ + (16 * m + px) * 48;
        bf16x8 Ah1 = mk8(ld4(ah + 8 * kc), ld4(ah + 8 * kc + 4));
        bf16x8 Ah2 = mk8(ld4(ah + 32 + 8 * kc), ld4(ah + 36 + 8 * kc));  // padded buf; garbage for kc>=2 ok (B=0)
        bf16x8 Al1 = mk8(ld4(al + 8 * kc), ld4(al + 8 * kc + 4));
        bf16x8 Al2 = mk8(ld4(al + 32 + 8 * kc), ld4(al + 36 + 8 * kc));
#pragma unroll
        for (int t = 0; t < 4; ++t) {
            const int pix = 64 * wv + 16 * t + px;
            const unsigned short* bh = Ph + pix * PSTR;
            bf16x8 Bh1 = mk8(ld4(bh + 8 * kc), ld4(bh + 8 * kc + 4));
            bf16x8 Bh2 = (kc < 2) ? mk8(ld4(bh + 32 + 8 * kc), ld4(bh + 36 + 8 * kc)) : zero8;
            f32x4 a = acc[m][t];
            a = __builtin_amdgcn_mfma_f32_16x16x32_bf16(Al1, Bh1, a, 0, 0, 0);
            a = __builtin_amdgcn_mfma_f32_16x16x32_bf16(Al2, Bh2, a, 0, 0, 0);
            a = __builtin_amdgcn_mfma_f32_16x16x32_bf16(Ah1, Bh1, a, 0, 0, 0);
            a = __builtin_amdgcn_mfma_f32_16x16x32_bf16(Ah2, Bh2, a, 0, 0, 0);
            acc[m][t] = a;
        }
    }
    // no barrier: D4 writes the same wave-private rows D3 just read

    // ---- D4: h = relu(acc) -> bf16, overlaying Ph. lane holds q=16m+4kc+r ----
#pragma unroll
    for (int t = 0; t < 4; ++t) {
        const int pix = 64 * wv + 16 * t + px;
        unsigned short* hrow = Ph + pix * PSTR;
#pragma unroll
        for (int m = 0; m < 3; ++m) {
            f32x4 a = acc[m][t];
            sh4 hv;
            hv.x = (short)f2bf(fmaxf(a[0], 0.0f));
            hv.y = (short)f2bf(fmaxf(a[1], 0.0f));
            hv.z = (short)f2bf(fmaxf(a[2], 0.0f));
            hv.w = (short)f2bf(fmaxf(a[3], 0.0f));
            *(sh4*)(hrow + 16 * m + 4 * kc) = hv;
        }
    }
    // no barrier: D5 reads the same wave-private rows

    // ---- D5: cur = (w2h+w2l) x H + raw*gate; store ----
    {
        const unsigned short* ah = w2h_ + px * 48;
        const unsigned short* al = w2l_ + px * 48;
        bf16x8 A2h1 = mk8(ld4(ah + 8 * kc), ld4(ah + 8 * kc + 4));
        bf16x8 A2h2 = mk8(ld4(ah + 32 + 8 * kc), ld4(ah + 36 + 8 * kc));
        bf16x8 A2l1 = mk8(ld4(al + 8 * kc), ld4(al + 8 * kc + 4));
        bf16x8 A2l2 = mk8(ld4(al + 32 + 8 * kc), ld4(al + 36 + 8 * kc));

        float gv[4];
#pragma unroll
        for (int t = 0; t < 4; ++t) gv[t] = gateArr[(4 * wv + t) * 16 + px];

        f32x4 q[4];
#pragma unroll
        for (int t = 0; t < 4; ++t) q[t] = 0.0f;
#pragma unroll
        for (int t = 0; t < 4; ++t) {
            const int pix = 64 * wv + 16 * t + px;
            const unsigned short* bh = Ph + pix * PSTR;
            bf16x8 B1 = mk8(ld4(bh + 8 * kc), ld4(bh + 8 * kc + 4));
            bf16x8 B2 = (kc < 2) ? mk8(ld4(bh + 32 + 8 * kc), ld4(bh + 36 + 8 * kc)) : zero8;
            f32x4 a = q[t];
            a = __builtin_amdgcn_mfma_f32_16x16x32_bf16(A2l1, B1, a, 0, 0, 0);
            a = __builtin_amdgcn_mfma_f32_16x16x32_bf16(A2l2, B2, a, 0, 0, 0);
            a = __builtin_amdgcn_mfma_f32_16x16x32_bf16(A2h1, B1, a, 0, 0, 0);
            a = __builtin_amdgcn_mfma_f32_16x16x32_bf16(A2h2, B2, a, 0, 0, 0);
            q[t] = a;
        }

        float* ob = cout + (size_t)n * CH * HWSZ;
#pragma unroll
        for (int t = 0; t < 4; ++t) {
            const int rowoff = (by + 4 * wv + t) * WW + bx + px;
#pragma unroll
            for (int r = 0; r < 4; ++r)
                ob[(size_t)(4 * kc + r) * HWSZ + rowoff] = q[t][r] + raw[t][r] * gv[t];
        }
    }
}

// ---------------- final: apply gate(30), emit channels 1..10 ----------------
__global__ __launch_bounds__(256) void final_kernel(
    const float* __restrict__ cur, const uint8_t* __restrict__ pre,
    float* __restrict__ out) {
    int i = blockIdx.x * 256 + threadIdx.x;        // over NIMG*H*W
    if (i >= NIMG * HWSZ) return;
    int x = i % WW, y = (i / WW) % HH, n = i / HWSZ;
    const float* c0 = cur + (size_t)n * CH * HWSZ;
    float pm = -1e30f;
    for (int dy = -1; dy <= 1; ++dy) {
        int yy = y + dy;
        if ((unsigned)yy >= HH) continue;
        for (int dx = -1; dx <= 1; ++dx) {
            int xx = x + dx;
            if ((unsigned)xx >= WW) continue;
            pm = fmaxf(pm, c0[yy * WW + xx]);
        }
    }
    const bool alive = pre[i] && (pm > THR);
    float* ob = out + (size_t)n * 10 * HWSZ + y * WW + x;
#pragma unroll
    for (int k = 1; k <= 10; ++k)
        ob[(k - 1) * HWSZ] = alive ? c0[k * HWSZ + y * WW + x] : 0.0f;
}

extern "C" void kernel_launch(void* const* d_in, const int* in_sizes, int n_in,
                              void* d_out, int out_size, void* d_ws, size_t ws_size,
                              hipStream_t stream) {
    const float* inp = (const float*)d_in[0];
    const float* w1  = (const float*)d_in[1];
    const float* w2  = (const float*)d_in[2];
    float* out = (float*)d_out;

    const size_t SE = (size_t)NIMG * CH * HWSZ;    // 8,388,608 floats
    float* bufA = (float*)d_ws;
    float* bufB = bufA + SE;
    uint8_t* bitsA = (uint8_t*)(bufB + SE);
    uint8_t* bitsB = bitsA + (size_t)NIMG * HWSZ;
    // weight fragments (bf16), padded +32 shorts so chunk-2 A reads stay in-bounds
    unsigned short* w1h = (unsigned short*)(bitsB + (size_t)NIMG * HWSZ);
    unsigned short* w1l = w1h + (48 * 48 + 32);
    unsigned short* w2h = w1l + (48 * 48 + 32);
    unsigned short* w2l = w2h + (16 * 48 + 32);

    init_kernel<<<((int)SE + 255) / 256, 256, 0, stream>>>(inp, bufA);
    prepack<<<1, 256, 0, stream>>>(w1, w2, w1h, w1l, w2h, w2l);

    dim3 grid(WW / TILE, HH / TILE, NIMG);
    float* src = bufA;
    float* dst = bufB;
    uint8_t* pin = bitsB;   // unused on first iter (gate=0)
    uint8_t* pout = bitsA;
    for (int it = 0; it < NUM_ITER; ++it) {
        step_kernel<<<grid, 256, 0, stream>>>(src, dst, pin, pout,
                                              w1h, w1l, w2h, w2l,
                                              it == 0 ? 0 : 1);
        float* t = src; src = dst; dst = t;
        uint8_t* tb = pin; pin = pout; pout = tb;
    }
    // after loop: src = cur(30), pin = pre(30) bits
    final_kernel<<<(NIMG * HWSZ + 255) / 256, 256, 0, stream>>>(src, pin, out);
}

// Round 4
// 1322.291 us; speedup vs baseline: 1.3814x; 1.3814x over previous
//
#include <hip/hip_runtime.h>
#include <stdint.h>

#define HH 128
#define WW 128
#define NIMG 32
#define CH 16
#define TILE 16
#define LW 20            // 16 + 2*2 halo
#define LA (LW * LW)     // 400 floats per channel plane
#define NUM_ITER 30
#define THR 0.1f
#define HWSZ (HH * WW)

#define PSTR 52                        // P/H row stride in bf16 elems (104 B)
#define CS_BYTES (17 * LA * 4)         // 27200 B: 17 planes (phases A-D1)
#define SMEM_BYTES CS_BYTES            // 27200 B -> 5 blocks/CU

typedef __attribute__((ext_vector_type(8))) short bf16x8;
typedef __attribute__((ext_vector_type(4))) float f32x4;
typedef __attribute__((ext_vector_type(4))) short sh4;

__device__ __forceinline__ unsigned short f2bf(float x) {
    union { float f; unsigned u; } v; v.f = x;
    return (unsigned short)((v.u + 0x7fffu + ((v.u >> 16) & 1u)) >> 16);  // RNE
}
__device__ __forceinline__ float bf2f(unsigned short h) {
    union { unsigned u; float f; } v; v.u = ((unsigned)h) << 16; return v.f;
}
__device__ __forceinline__ bf16x8 mk8(sh4 a, sh4 b) {
    bf16x8 r;
    r[0] = a.x; r[1] = a.y; r[2] = a.z; r[3] = a.w;
    r[4] = b.x; r[5] = b.y; r[6] = b.z; r[7] = b.w;
    return r;
}
__device__ __forceinline__ sh4 ld4(const unsigned short* p) {
    return *(const sh4*)p;
}

// ---------------- init: build 16-ch cell state from 10-ch input ----------------
__global__ __launch_bounds__(256) void init_kernel(const float* __restrict__ inp,
                                                   float* __restrict__ cell) {
    int i = blockIdx.x * 256 + threadIdx.x;
    if (i >= NIMG * CH * HWSZ) return;
    int hw = i % HWSZ;
    int c  = (i / HWSZ) % CH;
    int n  = i / (CH * HWSZ);
    float v;
    if (c == 0)       v = 1.0f - inp[(n * 10 + 0) * HWSZ + hw];
    else if (c <= 10) v = inp[(n * 10 + (c - 1)) * HWSZ + hw];
    else              v = 0.0f;
    cell[i] = v;
}

// ---------------- weight prepack: bf16 hi/lo split, row-major ----
__global__ void prepack(const float* __restrict__ w1, const float* __restrict__ w2,
                        unsigned short* __restrict__ w1h, unsigned short* __restrict__ w1l,
                        unsigned short* __restrict__ w2h, unsigned short* __restrict__ w2l) {
    int i = threadIdx.x;
    for (int k = i; k < 48 * 48; k += 256) {
        float f = w1[k];
        unsigned short h = f2bf(f);
        w1h[k] = h;
        w1l[k] = f2bf(f - bf2f(h));
    }
    for (int k = i; k < 16 * 48; k += 256) {
        float f = w2[k];
        unsigned short h = f2bf(f);
        w2h[k] = h;
        w2l[k] = f2bf(f - bf2f(h));
    }
}

// perception: p[0..15]=center, p[16..31]=sobel-x, p[32..47]=sobel-y
__device__ __forceinline__ void perception_at(const float* cs, int base, float* p) {
#pragma unroll
    for (int c = 0; c < CH; ++c) {
        const float* cc = cs + c * LA;
        float c00 = cc[base - LW - 1], c01 = cc[base - LW], c02 = cc[base - LW + 1];
        float c10 = cc[base - 1],      c11 = cc[base],      c12 = cc[base + 1];
        float c20 = cc[base + LW - 1], c21 = cc[base + LW], c22 = cc[base + LW + 1];
        p[c]      = c11;
        p[16 + c] = (c02 - c00 + 2.0f * (c12 - c10) + c22 - c20) * 0.125f;
        p[32 + c] = (c20 - c00 + 2.0f * (c21 - c01) + c22 - c02) * 0.125f;
    }
}

// ---------------- one fused CA step (MFMA matmuls, R4) ----------------
// R4 vs R3: residual no longer reloaded from GLOBAL (R3's raw[] added ~64MB
// HBM/step -> real-bench regression). The gated fp32 state already lives in
// cs after B+C, so each lane reads its 16 D5-residuals straight from LDS in
// the D1 window (bit-identical values, zero HBM). gateArr dead -> deleted.
// LDS 27200 B. Barriers: 3 (D2..D5 touch wave-private Ph rows only).
__global__ __launch_bounds__(256, 5) void step_kernel(
    const float* __restrict__ cin, float* __restrict__ cout,
    const uint8_t* __restrict__ pre_in, uint8_t* __restrict__ pre_out,
    const unsigned short* __restrict__ w1h_, const unsigned short* __restrict__ w1l_,
    const unsigned short* __restrict__ w2h_, const unsigned short* __restrict__ w2l_,
    int gate) {

    __shared__ __align__(16) char smem[SMEM_BYTES];
    float* cs = (float*)smem;                       // 17 planes x 400 floats
    unsigned short* Ph = (unsigned short*)smem;     // [256][PSTR] bf16 (overlays cs)

    const int tid = threadIdx.x;
    const int tx = tid & 15, ty = tid >> 4;
    const int lane = tid & 63;
    const int wv = tid >> 6;            // wave id: pixels [64*wv, 64*wv+64)
    const int px = lane & 15;           // col within 16-tile
    const int kc = lane >> 4;           // k-chunk id (0..3)
    const int bx = blockIdx.x * TILE, by = blockIdx.y * TILE;
    const int n = blockIdx.z;
    const float* cbase = cin + (size_t)n * CH * HWSZ;
    const uint8_t* pbase = pre_in + (size_t)n * HWSZ;

    // ---- hoisted coords: full 20x20 positions (raw ch0), two per thread ----
    const int lyA = tid / 20, lxA = tid % 20;
    const int gyA = by + lyA - 2, gxA = bx + lxA - 2;
    const bool okA = ((unsigned)gyA < HH) && ((unsigned)gxA < WW);
    const int offA = gyA * WW + gxA;

    const int rB = tid + 256;                  // valid when tid < 144
    const int lyB = rB / 20, lxB = rB % 20;
    const int gyB = by + lyB - 2, gxB = bx + lxB - 2;
    const bool okB = ((unsigned)gyB < HH) && ((unsigned)gxB < WW);
    const int offB = gyB * WW + gxB;

    // ---- hoisted coords: 18x18 region positions, two per thread ----
    const int j0 = tid;                        // always < 324
    const int jy0 = j0 / 18, jx0 = j0 % 18;
    const int gy0 = by + jy0 - 1, gx0 = bx + jx0 - 1;
    const bool ok0 = ((unsigned)gy0 < HH) && ((unsigned)gx0 < WW);
    const int goff0 = gy0 * WW + gx0;
    const int lpos0 = (jy0 + 1) * LW + (jx0 + 1);

    const int j1 = tid + 256;                  // valid when tid < 68
    const int jy1 = j1 / 18, jx1 = j1 % 18;
    const int gy1 = by + jy1 - 1, gx1 = bx + jx1 - 1;
    const bool ok1 = ((unsigned)gy1 < HH) && ((unsigned)gx1 < WW);
    const int goff1 = gy1 * WW + gx1;
    const int lpos1 = (jy1 + 1) * LW + (jx1 + 1);
    const bool hasB = (tid < 68);

    // ---- A: stage raw ch0 (plane 16) AND pre-issue all global loads ----
    cs[CH * LA + tid] = okA ? cbase[offA] : 0.0f;
    if (tid < 144) cs[CH * LA + rB] = okB ? cbase[offB] : 0.0f;

    float st0[CH - 1];
    {
        const float* gp = cbase + goff0;
#pragma unroll
        for (int c = 1; c < CH; ++c) st0[c - 1] = ok0 ? gp[c * HWSZ] : 0.0f;
    }
    int pv0 = 1;
    if (gate) pv0 = ok0 ? (int)pbase[goff0] : 0;

    float st1[CH - 1];
    int pv1 = 1;
    if (hasB) {
        const float* gp = cbase + goff1;
#pragma unroll
        for (int c = 1; c < CH; ++c) st1[c - 1] = ok1 ? gp[c * HWSZ] : 0.0f;
        if (gate) pv1 = ok1 ? (int)pbase[goff1] : 0;
    }
    __syncthreads();   // sync1

    // ---- B+C fused: gate from raw plane 16; gated writes to planes 0..15 ----
    {
        const float* rp = cs + CH * LA;
        float pm = -1e30f;
#pragma unroll
        for (int dy = -1; dy <= 1; ++dy)
#pragma unroll
            for (int dx = -1; dx <= 1; ++dx)
                pm = fmaxf(pm, rp[lpos0 + dy * LW + dx]);
        float g0 = 1.0f;
        if (gate) g0 = (pv0 && pm > THR) ? 1.0f : 0.0f;
        cs[lpos0] = rp[lpos0] * g0;
#pragma unroll
        for (int c = 1; c < CH; ++c) cs[c * LA + lpos0] = st0[c - 1] * g0;
    }
    if (hasB) {
        const float* rp = cs + CH * LA;
        float pm = -1e30f;
#pragma unroll
        for (int dy = -1; dy <= 1; ++dy)
#pragma unroll
            for (int dx = -1; dx <= 1; ++dx)
                pm = fmaxf(pm, rp[lpos1 + dy * LW + dx]);
        float g1 = 1.0f;
        if (gate) g1 = (pv1 && pm > THR) ? 1.0f : 0.0f;
        cs[lpos1] = rp[lpos1] * g1;
#pragma unroll
        for (int c = 1; c < CH; ++c) cs[c * LA + lpos1] = st1[c - 1] * g1;
    }
    __syncthreads();   // sync2

    // ---- D1: pre(i) bits + per-thread perception + residual grab (reads cs) ----
    const int base = (ty + 2) * LW + (tx + 2);
    float pm = -1e30f;
#pragma unroll
    for (int dy = -1; dy <= 1; ++dy)
#pragma unroll
        for (int dx = -1; dx <= 1; ++dx)
            pm = fmaxf(pm, cs[base + dy * LW + dx]);
    pre_out[(size_t)n * HWSZ + (size_t)(by + ty) * WW + (bx + tx)] = (pm > THR) ? 1 : 0;

    float p[48];
    perception_at(cs, base, p);

    // residual for this lane's D5 output assignment: pixel (4wv+t, px),
    // channel 4kc+r -- the gated fp32 state, read from cs before overlay.
    float res[4][4];
#pragma unroll
    for (int t = 0; t < 4; ++t) {
        const int lp = (4 * wv + t + 2) * LW + (px + 2);
#pragma unroll
        for (int r = 0; r < 4; ++r)
            res[t][r] = cs[(4 * kc + r) * LA + lp];
    }
    __syncthreads();   // sync3: all cs reads done; Ph may now overlay cs

    // ---- D2: p -> bf16 hi into LDS (row = tid; wave-private rows) ----
    {
        unsigned short* hrow = Ph + tid * PSTR;
#pragma unroll
        for (int j = 0; j < 12; ++j) {
            sh4 hv;
            hv.x = (short)f2bf(p[4 * j + 0]);
            hv.y = (short)f2bf(p[4 * j + 1]);
            hv.z = (short)f2bf(p[4 * j + 2]);
            hv.w = (short)f2bf(p[4 * j + 3]);
            *(sh4*)(hrow + 4 * j) = hv;
        }
    }
    // no barrier: D3 B-reads are wave-private rows, DS pipe is in-order per wave

    // ---- D3: h = relu(w1 x P) via MFMA (2-product: (w1h+w1l) x Phi) ----
    const sh4 z4 = (sh4)0;
    const bf16x8 zero8 = mk8(z4, z4);

    f32x4 acc[3][4];
#pragma unroll
    for (int m = 0; m < 3; ++m)
#pragma unroll
        for (int t = 0; t < 4; ++t) acc[m][t] = 0.0f;

#pragma unroll
    for (int m = 0; m < 3; ++m) {
        const unsigned short* ah = w1h_ + (16 * m + px) * 48;
        const unsigned short* al = w1l_ + (16 * m + px) * 48;
        bf16x8 Ah1 = mk8(ld4(ah + 8 * kc), ld4(ah + 8 * kc + 4));
        bf16x8 Ah2 = mk8(ld4(ah + 32 + 8 * kc), ld4(ah + 36 + 8 * kc));  // padded buf; garbage for kc>=2 ok (B=0)
        bf16x8 Al1 = mk8(ld4(al + 8 * kc), ld4(al + 8 * kc + 4));
        bf16x8 Al2 = mk8(ld4(al + 32 + 8 * kc), ld4(al + 36 + 8 * kc));
#pragma unroll
        for (int t = 0; t < 4; ++t) {
            const int pix = 64 * wv + 16 * t + px;
            const unsigned short* bh = Ph + pix * PSTR;
            bf16x8 Bh1 = mk8(ld4(bh + 8 * kc), ld4(bh + 8 * kc + 4));
            bf16x8 Bh2 = (kc < 2) ? mk8(ld4(bh + 32 + 8 * kc), ld4(bh + 36 + 8 * kc)) : zero8;
            f32x4 a = acc[m][t];
            a = __builtin_amdgcn_mfma_f32_16x16x32_bf16(Al1, Bh1, a, 0, 0, 0);
            a = __builtin_amdgcn_mfma_f32_16x16x32_bf16(Al2, Bh2, a, 0, 0, 0);
            a = __builtin_amdgcn_mfma_f32_16x16x32_bf16(Ah1, Bh1, a, 0, 0, 0);
            a = __builtin_amdgcn_mfma_f32_16x16x32_bf16(Ah2, Bh2, a, 0, 0, 0);
            acc[m][t] = a;
        }
    }
    // no barrier: D4 writes the same wave-private rows D3 just read

    // ---- D4: h = relu(acc) -> bf16, overlaying Ph. lane holds q=16m+4kc+r ----
#pragma unroll
    for (int t = 0; t < 4; ++t) {
        const int pix = 64 * wv + 16 * t + px;
        unsigned short* hrow = Ph + pix * PSTR;
#pragma unroll
        for (int m = 0; m < 3; ++m) {
            f32x4 a = acc[m][t];
            sh4 hv;
            hv.x = (short)f2bf(fmaxf(a[0], 0.0f));
            hv.y = (short)f2bf(fmaxf(a[1], 0.0f));
            hv.z = (short)f2bf(fmaxf(a[2], 0.0f));
            hv.w = (short)f2bf(fmaxf(a[3], 0.0f));
            *(sh4*)(hrow + 16 * m + 4 * kc) = hv;
        }
    }
    // no barrier: D5 reads the same wave-private rows

    // ---- D5: cur = (w2h+w2l) x H + res; store ----
    {
        const unsigned short* ah = w2h_ + px * 48;
        const unsigned short* al = w2l_ + px * 48;
        bf16x8 A2h1 = mk8(ld4(ah + 8 * kc), ld4(ah + 8 * kc + 4));
        bf16x8 A2h2 = mk8(ld4(ah + 32 + 8 * kc), ld4(ah + 36 + 8 * kc));
        bf16x8 A2l1 = mk8(ld4(al + 8 * kc), ld4(al + 8 * kc + 4));
        bf16x8 A2l2 = mk8(ld4(al + 32 + 8 * kc), ld4(al + 36 + 8 * kc));

        f32x4 q[4];
#pragma unroll
        for (int t = 0; t < 4; ++t) q[t] = 0.0f;
#pragma unroll
        for (int t = 0; t < 4; ++t) {
            const int pix = 64 * wv + 16 * t + px;
            const unsigned short* bh = Ph + pix * PSTR;
            bf16x8 B1 = mk8(ld4(bh + 8 * kc), ld4(bh + 8 * kc + 4));
            bf16x8 B2 = (kc < 2) ? mk8(ld4(bh + 32 + 8 * kc), ld4(bh + 36 + 8 * kc)) : zero8;
            f32x4 a = q[t];
            a = __builtin_amdgcn_mfma_f32_16x16x32_bf16(A2l1, B1, a, 0, 0, 0);
            a = __builtin_amdgcn_mfma_f32_16x16x32_bf16(A2l2, B2, a, 0, 0, 0);
            a = __builtin_amdgcn_mfma_f32_16x16x32_bf16(A2h1, B1, a, 0, 0, 0);
            a = __builtin_amdgcn_mfma_f32_16x16x32_bf16(A2h2, B2, a, 0, 0, 0);
            q[t] = a;
        }

        float* ob = cout + (size_t)n * CH * HWSZ;
#pragma unroll
        for (int t = 0; t < 4; ++t) {
            const int rowoff = (by + 4 * wv + t) * WW + bx + px;
#pragma unroll
            for (int r = 0; r < 4; ++r)
                ob[(size_t)(4 * kc + r) * HWSZ + rowoff] = q[t][r] + res[t][r];
        }
    }
}

// ---------------- final: apply gate(30), emit channels 1..10 ----------------
__global__ __launch_bounds__(256) void final_kernel(
    const float* __restrict__ cur, const uint8_t* __restrict__ pre,
    float* __restrict__ out) {
    int i = blockIdx.x * 256 + threadIdx.x;        // over NIMG*H*W
    if (i >= NIMG * HWSZ) return;
    int x = i % WW, y = (i / WW) % HH, n = i / HWSZ;
    const float* c0 = cur + (size_t)n * CH * HWSZ;
    float pm = -1e30f;
    for (int dy = -1; dy <= 1; ++dy) {
        int yy = y + dy;
        if ((unsigned)yy >= HH) continue;
        for (int dx = -1; dx <= 1; ++dx) {
            int xx = x + dx;
            if ((unsigned)xx >= WW) continue;
            pm = fmaxf(pm, c0[yy * WW + xx]);
        }
    }
    const bool alive = pre[i] && (pm > THR);
    float* ob = out + (size_t)n * 10 * HWSZ + y * WW + x;
#pragma unroll
    for (int k = 1; k <= 10; ++k)
        ob[(k - 1) * HWSZ] = alive ? c0[k * HWSZ + y * WW + x] : 0.0f;
}

extern "C" void kernel_launch(void* const* d_in, const int* in_sizes, int n_in,
                              void* d_out, int out_size, void* d_ws, size_t ws_size,
                              hipStream_t stream) {
    const float* inp = (const float*)d_in[0];
    const float* w1  = (const float*)d_in[1];
    const float* w2  = (const float*)d_in[2];
    float* out = (float*)d_out;

    const size_t SE = (size_t)NIMG * CH * HWSZ;    // 8,388,608 floats
    float* bufA = (float*)d_ws;
    float* bufB = bufA + SE;
    uint8_t* bitsA = (uint8_t*)(bufB + SE);
    uint8_t* bitsB = bitsA + (size_t)NIMG * HWSZ;
    // weight fragments (bf16), padded +32 shorts so chunk-2 A reads stay in-bounds
    unsigned short* w1h = (unsigned short*)(bitsB + (size_t)NIMG * HWSZ);
    unsigned short* w1l = w1h + (48 * 48 + 32);
    unsigned short* w2h = w1l + (48 * 48 + 32);
    unsigned short* w2l = w2h + (16 * 48 + 32);

    init_kernel<<<((int)SE + 255) / 256, 256, 0, stream>>>(inp, bufA);
    prepack<<<1, 256, 0, stream>>>(w1, w2, w1h, w1l, w2h, w2l);

    dim3 grid(WW / TILE, HH / TILE, NIMG);
    float* src = bufA;
    float* dst = bufB;
    uint8_t* pin = bitsB;   // unused on first iter (gate=0)
    uint8_t* pout = bitsA;
    for (int it = 0; it < NUM_ITER; ++it) {
        step_kernel<<<grid, 256, 0, stream>>>(src, dst, pin, pout,
                                              w1h, w1l, w2h, w2l,
                                              it == 0 ? 0 : 1);
        float* t = src; src = dst; dst = t;
        uint8_t* tb = pin; pin = pout; pout = tb;
    }
    // after loop: src = cur(30), pin = pre(30) bits
    final_kernel<<<(NIMG * HWSZ + 255) / 256, 256, 0, stream>>>(src, pin, out);
}

// Round 5
// 1004.616 us; speedup vs baseline: 1.8182x; 1.3162x over previous
//
#include <hip/hip_runtime.h>
#include <hip/hip_bf16.h>
#include <stdint.h>

#define HH 128
#define WW 128
#define NIMG 32
#define CH 16
#define TILE 16
#define LW 20            // 16 + 2*2 halo
#define LA (LW * LW)     // 400 floats per channel plane
#define NUM_ITER 30
#define THR 0.1f
#define HWSZ (HH * WW)

#define PSTR 52                        // P/H row stride in bf16 elems (104 B)
#define CS_BYTES (17 * LA * 4)         // 27200 B: 17 planes (phases A-D1)
#define SMEM_BYTES CS_BYTES            // 27200 B -> 5 blocks/CU

typedef __attribute__((ext_vector_type(8))) short bf16x8;
typedef __attribute__((ext_vector_type(4))) float f32x4;
typedef __attribute__((ext_vector_type(4))) short sh4;

// hardware RNE f32->bf16 (compiler emits v_cvt_pk_bf16_f32; bit-identical to
// manual RNE round-to-nearest-even)
__device__ __forceinline__ unsigned short f2bf(float x) {
    return __builtin_bit_cast(unsigned short, __float2bfloat16(x));
}
__device__ __forceinline__ float bf2f(unsigned short h) {
    union { unsigned u; float f; } v; v.u = ((unsigned)h) << 16; return v.f;
}
__device__ __forceinline__ bf16x8 mk8(sh4 a, sh4 b) {
    bf16x8 r;
    r[0] = a.x; r[1] = a.y; r[2] = a.z; r[3] = a.w;
    r[4] = b.x; r[5] = b.y; r[6] = b.z; r[7] = b.w;
    return r;
}
__device__ __forceinline__ sh4 ld4(const unsigned short* p) {
    return *(const sh4*)p;
}
// 9-point max as v_max3-fusable triples (4 insts, log-depth chain)
__device__ __forceinline__ float max9(const float* p, int idx, int stride) {
    float a = fmaxf(fmaxf(p[idx - stride - 1], p[idx - stride]), p[idx - stride + 1]);
    float b = fmaxf(fmaxf(p[idx - 1],          p[idx]),          p[idx + 1]);
    float c = fmaxf(fmaxf(p[idx + stride - 1], p[idx + stride]), p[idx + stride + 1]);
    return fmaxf(fmaxf(a, b), c);
}

// ---------------- init: build 16-ch cell state from 10-ch input ----------------
__global__ __launch_bounds__(256) void init_kernel(const float* __restrict__ inp,
                                                   float* __restrict__ cell) {
    int i = blockIdx.x * 256 + threadIdx.x;
    if (i >= NIMG * CH * HWSZ) return;
    int hw = i % HWSZ;
    int c  = (i / HWSZ) % CH;
    int n  = i / (CH * HWSZ);
    float v;
    if (c == 0)       v = 1.0f - inp[(n * 10 + 0) * HWSZ + hw];
    else if (c <= 10) v = inp[(n * 10 + (c - 1)) * HWSZ + hw];
    else              v = 0.0f;
    cell[i] = v;
}

// ---------------- weight prepack: bf16 hi/lo split, row-major ----
__global__ void prepack(const float* __restrict__ w1, const float* __restrict__ w2,
                        unsigned short* __restrict__ w1h, unsigned short* __restrict__ w1l,
                        unsigned short* __restrict__ w2h, unsigned short* __restrict__ w2l) {
    int i = threadIdx.x;
    for (int k = i; k < 48 * 48; k += 256) {
        float f = w1[k];
        unsigned short h = f2bf(f);
        w1h[k] = h;
        w1l[k] = f2bf(f - bf2f(h));
    }
    for (int k = i; k < 16 * 48; k += 256) {
        float f = w2[k];
        unsigned short h = f2bf(f);
        w2h[k] = h;
        w2l[k] = f2bf(f - bf2f(h));
    }
}

// perception: p[0..15]=center, p[16..31]=sobel-x, p[32..47]=sobel-y
__device__ __forceinline__ void perception_at(const float* cs, int base, float* p) {
#pragma unroll
    for (int c = 0; c < CH; ++c) {
        const float* cc = cs + c * LA;
        float c00 = cc[base - LW - 1], c01 = cc[base - LW], c02 = cc[base - LW + 1];
        float c10 = cc[base - 1],      c11 = cc[base],      c12 = cc[base + 1];
        float c20 = cc[base + LW - 1], c21 = cc[base + LW], c22 = cc[base + LW + 1];
        p[c]      = c11;
        p[16 + c] = (c02 - c00 + 2.0f * (c12 - c10) + c22 - c20) * 0.125f;
        p[32 + c] = (c20 - c00 + 2.0f * (c21 - c01) + c22 - c02) * 0.125f;
    }
}

// ---------------- one fused CA step (MFMA matmuls, R5) ----------------
// R5 vs R4: (1) f2bf -> hardware v_cvt (compiler-lowered; RNE-identical),
// 9-pt maxes tree-shaped for v_max3 fusion. (2) XCD-aware block swizzle:
// 1-D grid, wgid = ((n&3)*64 + tile)*8 + (n>>2), assuming wgid%8 -> XCD.
// Each XCD then owns 4 whole images: all halo-line sharing is same-L2,
// cutting cross-XCD line duplication (R4: FETCH 72MB vs ~43MB ideal).
// LDS 27200 B -> 5 blocks/CU. Barriers: 3.
__global__ __launch_bounds__(256, 5) void step_kernel(
    const float* __restrict__ cin, float* __restrict__ cout,
    const uint8_t* __restrict__ pre_in, uint8_t* __restrict__ pre_out,
    const unsigned short* __restrict__ w1h_, const unsigned short* __restrict__ w1l_,
    const unsigned short* __restrict__ w2h_, const unsigned short* __restrict__ w2l_,
    int gate) {

    __shared__ __align__(16) char smem[SMEM_BYTES];
    float* cs = (float*)smem;                       // 17 planes x 400 floats
    unsigned short* Ph = (unsigned short*)smem;     // [256][PSTR] bf16 (overlays cs)

    const int tid = threadIdx.x;
    const int tx = tid & 15, ty = tid >> 4;
    const int lane = tid & 63;
    const int wv = tid >> 6;            // wave id: pixels [64*wv, 64*wv+64)
    const int px = lane & 15;           // col within 16-tile
    const int kc = lane >> 4;           // k-chunk id (0..3)

    // ---- XCD-aware decode: wgid%8 = XCD (assumed); each XCD owns 4 images ----
    const int wgid = blockIdx.x;
    const int xcd = wgid & 7;
    const int s   = wgid >> 3;              // 0..255 per XCD
    const int n   = (xcd << 2) + (s >> 6);  // image
    const int t_  = s & 63;                 // tile within image
    const int bx = (t_ & 7) * TILE;
    const int by = (t_ >> 3) * TILE;

    const float* cbase = cin + (size_t)n * CH * HWSZ;
    const uint8_t* pbase = pre_in + (size_t)n * HWSZ;

    // ---- hoisted coords: full 20x20 positions (raw ch0), two per thread ----
    const int lyA = tid / 20, lxA = tid % 20;
    const int gyA = by + lyA - 2, gxA = bx + lxA - 2;
    const bool okA = ((unsigned)gyA < HH) && ((unsigned)gxA < WW);
    const int offA = gyA * WW + gxA;

    const int rB = tid + 256;                  // valid when tid < 144
    const int lyB = rB / 20, lxB = rB % 20;
    const int gyB = by + lyB - 2, gxB = bx + lxB - 2;
    const bool okB = ((unsigned)gyB < HH) && ((unsigned)gxB < WW);
    const int offB = gyB * WW + gxB;

    // ---- hoisted coords: 18x18 region positions, two per thread ----
    const int j0 = tid;                        // always < 324
    const int jy0 = j0 / 18, jx0 = j0 % 18;
    const int gy0 = by + jy0 - 1, gx0 = bx + jx0 - 1;
    const bool ok0 = ((unsigned)gy0 < HH) && ((unsigned)gx0 < WW);
    const int goff0 = gy0 * WW + gx0;
    const int lpos0 = (jy0 + 1) * LW + (jx0 + 1);

    const int j1 = tid + 256;                  // valid when tid < 68
    const int jy1 = j1 / 18, jx1 = j1 % 18;
    const int gy1 = by + jy1 - 1, gx1 = bx + jx1 - 1;
    const bool ok1 = ((unsigned)gy1 < HH) && ((unsigned)gx1 < WW);
    const int goff1 = gy1 * WW + gx1;
    const int lpos1 = (jy1 + 1) * LW + (jx1 + 1);
    const bool hasB = (tid < 68);

    // ---- A: stage raw ch0 (plane 16) AND pre-issue all global loads ----
    cs[CH * LA + tid] = okA ? cbase[offA] : 0.0f;
    if (tid < 144) cs[CH * LA + rB] = okB ? cbase[offB] : 0.0f;

    float st0[CH - 1];
    {
        const float* gp = cbase + goff0;
#pragma unroll
        for (int c = 1; c < CH; ++c) st0[c - 1] = ok0 ? gp[c * HWSZ] : 0.0f;
    }
    int pv0 = 1;
    if (gate) pv0 = ok0 ? (int)pbase[goff0] : 0;

    float st1[CH - 1];
    int pv1 = 1;
    if (hasB) {
        const float* gp = cbase + goff1;
#pragma unroll
        for (int c = 1; c < CH; ++c) st1[c - 1] = ok1 ? gp[c * HWSZ] : 0.0f;
        if (gate) pv1 = ok1 ? (int)pbase[goff1] : 0;
    }
    __syncthreads();   // sync1

    // ---- B+C fused: gate from raw plane 16; gated writes to planes 0..15 ----
    {
        const float* rp = cs + CH * LA;
        float pm = max9(rp, lpos0, LW);
        float g0 = 1.0f;
        if (gate) g0 = (pv0 && pm > THR) ? 1.0f : 0.0f;
        cs[lpos0] = rp[lpos0] * g0;
#pragma unroll
        for (int c = 1; c < CH; ++c) cs[c * LA + lpos0] = st0[c - 1] * g0;
    }
    if (hasB) {
        const float* rp = cs + CH * LA;
        float pm = max9(rp, lpos1, LW);
        float g1 = 1.0f;
        if (gate) g1 = (pv1 && pm > THR) ? 1.0f : 0.0f;
        cs[lpos1] = rp[lpos1] * g1;
#pragma unroll
        for (int c = 1; c < CH; ++c) cs[c * LA + lpos1] = st1[c - 1] * g1;
    }
    __syncthreads();   // sync2

    // ---- D1: pre(i) bits + per-thread perception + residual grab (reads cs) ----
    const int base = (ty + 2) * LW + (tx + 2);
    {
        float pm = max9(cs, base, LW);
        pre_out[(size_t)n * HWSZ + (size_t)(by + ty) * WW + (bx + tx)] = (pm > THR) ? 1 : 0;
    }

    float p[48];
    perception_at(cs, base, p);

    // residual for this lane's D5 output assignment: pixel (4wv+t, px),
    // channel 4kc+r -- the gated fp32 state, read from cs before overlay.
    float res[4][4];
#pragma unroll
    for (int t = 0; t < 4; ++t) {
        const int lp = (4 * wv + t + 2) * LW + (px + 2);
#pragma unroll
        for (int r = 0; r < 4; ++r)
            res[t][r] = cs[(4 * kc + r) * LA + lp];
    }
    __syncthreads();   // sync3: all cs reads done; Ph may now overlay cs

    // ---- D2: p -> bf16 hi into LDS (row = tid; wave-private rows) ----
    {
        unsigned short* hrow = Ph + tid * PSTR;
#pragma unroll
        for (int j = 0; j < 12; ++j) {
            sh4 hv;
            hv.x = (short)f2bf(p[4 * j + 0]);
            hv.y = (short)f2bf(p[4 * j + 1]);
            hv.z = (short)f2bf(p[4 * j + 2]);
            hv.w = (short)f2bf(p[4 * j + 3]);
            *(sh4*)(hrow + 4 * j) = hv;
        }
    }
    // no barrier: D3 B-reads are wave-private rows, DS pipe is in-order per wave

    // ---- D3: h = relu(w1 x P) via MFMA (2-product: (w1h+w1l) x Phi) ----
    const sh4 z4 = (sh4)0;
    const bf16x8 zero8 = mk8(z4, z4);

    f32x4 acc[3][4];
#pragma unroll
    for (int m = 0; m < 3; ++m)
#pragma unroll
        for (int t = 0; t < 4; ++t) acc[m][t] = 0.0f;

#pragma unroll
    for (int m = 0; m < 3; ++m) {
        const unsigned short* ah = w1h_ + (16 * m + px) * 48;
        const unsigned short* al = w1l_ + (16 * m + px) * 48;
        bf16x8 Ah1 = mk8(ld4(ah + 8 * kc), ld4(ah + 8 * kc + 4));
        bf16x8 Ah2 = mk8(ld4(ah + 32 + 8 * kc), ld4(ah + 36 + 8 * kc));  // padded buf; garbage for kc>=2 ok (B=0)
        bf16x8 Al1 = mk8(ld4(al + 8 * kc), ld4(al + 8 * kc + 4));
        bf16x8 Al2 = mk8(ld4(al + 32 + 8 * kc), ld4(al + 36 + 8 * kc));
#pragma unroll
        for (int t = 0; t < 4; ++t) {
            const int pix = 64 * wv + 16 * t + px;
            const unsigned short* bh = Ph + pix * PSTR;
            bf16x8 Bh1 = mk8(ld4(bh + 8 * kc), ld4(bh + 8 * kc + 4));
            bf16x8 Bh2 = (kc < 2) ? mk8(ld4(bh + 32 + 8 * kc), ld4(bh + 36 + 8 * kc)) : zero8;
            f32x4 a = acc[m][t];
            a = __builtin_amdgcn_mfma_f32_16x16x32_bf16(Al1, Bh1, a, 0, 0, 0);
            a = __builtin_amdgcn_mfma_f32_16x16x32_bf16(Al2, Bh2, a, 0, 0, 0);
            a = __builtin_amdgcn_mfma_f32_16x16x32_bf16(Ah1, Bh1, a, 0, 0, 0);
            a = __builtin_amdgcn_mfma_f32_16x16x32_bf16(Ah2, Bh2, a, 0, 0, 0);
            acc[m][t] = a;
        }
    }
    // no barrier: D4 writes the same wave-private rows D3 just read

    // ---- D4: h = relu(acc) -> bf16, overlaying Ph. lane holds q=16m+4kc+r ----
#pragma unroll
    for (int t = 0; t < 4; ++t) {
        const int pix = 64 * wv + 16 * t + px;
        unsigned short* hrow = Ph + pix * PSTR;
#pragma unroll
        for (int m = 0; m < 3; ++m) {
            f32x4 a = acc[m][t];
            sh4 hv;
            hv.x = (short)f2bf(fmaxf(a[0], 0.0f));
            hv.y = (short)f2bf(fmaxf(a[1], 0.0f));
            hv.z = (short)f2bf(fmaxf(a[2], 0.0f));
            hv.w = (short)f2bf(fmaxf(a[3], 0.0f));
            *(sh4*)(hrow + 16 * m + 4 * kc) = hv;
        }
    }
    // no barrier: D5 reads the same wave-private rows

    // ---- D5: cur = (w2h+w2l) x H + res; store ----
    {
        const unsigned short* ah = w2h_ + px * 48;
        const unsigned short* al = w2l_ + px * 48;
        bf16x8 A2h1 = mk8(ld4(ah + 8 * kc), ld4(ah + 8 * kc + 4));
        bf16x8 A2h2 = mk8(ld4(ah + 32 + 8 * kc), ld4(ah + 36 + 8 * kc));
        bf16x8 A2l1 = mk8(ld4(al + 8 * kc), ld4(al + 8 * kc + 4));
        bf16x8 A2l2 = mk8(ld4(al + 32 + 8 * kc), ld4(al + 36 + 8 * kc));

        f32x4 q[4];
#pragma unroll
        for (int t = 0; t < 4; ++t) q[t] = 0.0f;
#pragma unroll
        for (int t = 0; t < 4; ++t) {
            const int pix = 64 * wv + 16 * t + px;
            const unsigned short* bh = Ph + pix * PSTR;
            bf16x8 B1 = mk8(ld4(bh + 8 * kc), ld4(bh + 8 * kc + 4));
            bf16x8 B2 = (kc < 2) ? mk8(ld4(bh + 32 + 8 * kc), ld4(bh + 36 + 8 * kc)) : zero8;
            f32x4 a = q[t];
            a = __builtin_amdgcn_mfma_f32_16x16x32_bf16(A2l1, B1, a, 0, 0, 0);
            a = __builtin_amdgcn_mfma_f32_16x16x32_bf16(A2l2, B2, a, 0, 0, 0);
            a = __builtin_amdgcn_mfma_f32_16x16x32_bf16(A2h1, B1, a, 0, 0, 0);
            a = __builtin_amdgcn_mfma_f32_16x16x32_bf16(A2h2, B2, a, 0, 0, 0);
            q[t] = a;
        }

        float* ob = cout + (size_t)n * CH * HWSZ;
#pragma unroll
        for (int t = 0; t < 4; ++t) {
            const int rowoff = (by + 4 * wv + t) * WW + bx + px;
#pragma unroll
            for (int r = 0; r < 4; ++r)
                ob[(size_t)(4 * kc + r) * HWSZ + rowoff] = q[t][r] + res[t][r];
        }
    }
}

// ---------------- final: apply gate(30), emit channels 1..10 ----------------
__global__ __launch_bounds__(256) void final_kernel(
    const float* __restrict__ cur, const uint8_t* __restrict__ pre,
    float* __restrict__ out) {
    int i = blockIdx.x * 256 + threadIdx.x;        // over NIMG*H*W
    if (i >= NIMG * HWSZ) return;
    int x = i % WW, y = (i / WW) % HH, n = i / HWSZ;
    const float* c0 = cur + (size_t)n * CH * HWSZ;
    float pm = -1e30f;
    for (int dy = -1; dy <= 1; ++dy) {
        int yy = y + dy;
        if ((unsigned)yy >= HH) continue;
        for (int dx = -1; dx <= 1; ++dx) {
            int xx = x + dx;
            if ((unsigned)xx >= WW) continue;
            pm = fmaxf(pm, c0[yy * WW + xx]);
        }
    }
    const bool alive = pre[i] && (pm > THR);
    float* ob = out + (size_t)n * 10 * HWSZ + y * WW + x;
#pragma unroll
    for (int k = 1; k <= 10; ++k)
        ob[(k - 1) * HWSZ] = alive ? c0[k * HWSZ + y * WW + x] : 0.0f;
}

extern "C" void kernel_launch(void* const* d_in, const int* in_sizes, int n_in,
                              void* d_out, int out_size, void* d_ws, size_t ws_size,
                              hipStream_t stream) {
    const float* inp = (const float*)d_in[0];
    const float* w1  = (const float*)d_in[1];
    const float* w2  = (const float*)d_in[2];
    float* out = (float*)d_out;

    const size_t SE = (size_t)NIMG * CH * HWSZ;    // 8,388,608 floats
    float* bufA = (float*)d_ws;
    float* bufB = bufA + SE;
    uint8_t* bitsA = (uint8_t*)(bufB + SE);
    uint8_t* bitsB = bitsA + (size_t)NIMG * HWSZ;
    // weight fragments (bf16), padded +32 shorts so chunk-2 A reads stay in-bounds
    unsigned short* w1h = (unsigned short*)(bitsB + (size_t)NIMG * HWSZ);
    unsigned short* w1l = w1h + (48 * 48 + 32);
    unsigned short* w2h = w1l + (48 * 48 + 32);
    unsigned short* w2l = w2h + (16 * 48 + 32);

    init_kernel<<<((int)SE + 255) / 256, 256, 0, stream>>>(inp, bufA);
    prepack<<<1, 256, 0, stream>>>(w1, w2, w1h, w1l, w2h, w2l);

    const int nblk = (WW / TILE) * (HH / TILE) * NIMG;   // 2048, 1-D swizzled grid
    float* src = bufA;
    float* dst = bufB;
    uint8_t* pin = bitsB;   // unused on first iter (gate=0)
    uint8_t* pout = bitsA;
    for (int it = 0; it < NUM_ITER; ++it) {
        step_kernel<<<nblk, 256, 0, stream>>>(src, dst, pin, pout,
                                              w1h, w1l, w2h, w2l,
                                              it == 0 ? 0 : 1);
        float* t = src; src = dst; dst = t;
        uint8_t* tb = pin; pin = pout; pout = tb;
    }
    // after loop: src = cur(30), pin = pre(30) bits
    final_kernel<<<(NIMG * HWSZ + 255) / 256, 256, 0, stream>>>(src, pin, out);
}